// Round 11
// baseline (577.198 us; speedup 1.0000x reference)
//
#include <hip/hip_runtime.h>

#define N_NODES 50000
#define N_EDGES 800000
#define N_GRAPHS 64
#define NEG_SLOPE 0.2f
// 1/sqrt(1 + 1e-5), BN eval-mode scale
#define BN_RSQ 0.9999950000374997f
#define NB_SCAN ((N_NODES + 255) / 256)  // 196 blocks in the node-space scan

typedef __bf16 bf16x8 __attribute__((ext_vector_type(8)));
typedef float floatx4 __attribute__((ext_vector_type(4)));

__device__ __forceinline__ float lrelu(float v) { return v > 0.0f ? v : NEG_SLOPE * v; }

// bf16 <-> f32 (round-to-nearest-even)
__device__ __forceinline__ float b2f(unsigned short u) {
    return __uint_as_float(((unsigned int)u) << 16);
}
__device__ __forceinline__ unsigned short f2b(float f) {
    unsigned int u = __float_as_uint(f);
    return (unsigned short)((u + 0x7fffu + ((u >> 16) & 1u)) >> 16);
}
// unpack 2 bf16 from one dword (1 instr each: shl / and)
__device__ __forceinline__ float blo(unsigned int d) { return __uint_as_float(d << 16); }
__device__ __forceinline__ float bhi(unsigned int d) { return __uint_as_float(d & 0xffff0000u); }

// ---------------- fused prep: degree count + weight bf16 conversion ----------------
// W1 transposed to [n][k] (MFMA B-frag layout); W2/W3/W4 straight-cast [k][c].
__global__ void k_prep(const int* __restrict__ ei, int* __restrict__ deg,
                       const float* __restrict__ W1, const float* __restrict__ W2,
                       const float* __restrict__ W3, const float* __restrict__ W4,
                       unsigned short* __restrict__ Wt1, unsigned short* __restrict__ W2b,
                       unsigned short* __restrict__ W3b, unsigned short* __restrict__ W4b) {
    int i = blockIdx.x * 256 + threadIdx.x;
    if (i < 32768) {  // W1: 128x256 -> transpose
        int k = i >> 8, n = i & 255;
        Wt1[n * 128 + k] = f2b(W1[i]);
    } else if (i < 49152) {
        W2b[i - 32768] = f2b(W2[i - 32768]);
    } else if (i < 53248) {
        W3b[i - 49152] = f2b(W3[i - 49152]);
    } else if (i < 57344) {
        W4b[i - 53248] = f2b(W4[i - 53248]);
    }
    if (i < N_EDGES) atomicAdd(&deg[ei[N_EDGES + i]], 1);
}

// offsets via wave shuffle-scan + one atomic per wave; per-block degree histogram
// (LPT: bucket = 63 - min(deg,63) -> descending-degree sort, long blocks first);
// graph bounds (batch sorted).
__global__ __launch_bounds__(256) void k_offs(const int* __restrict__ deg, int* __restrict__ offs,
                                              int* __restrict__ total, const int* __restrict__ batch,
                                              int* __restrict__ bounds, int* __restrict__ bh) {
    __shared__ int lh[64];
    if (threadIdx.x < 64) lh[threadIdx.x] = 0;
    __syncthreads();
    if (blockIdx.x == 0 && threadIdx.x <= N_GRAPHS) {
        int g = threadIdx.x;
        int lo = 0, hi = N_NODES;
        while (lo < hi) {
            int mid = (lo + hi) >> 1;
            if (batch[mid] < g) lo = mid + 1; else hi = mid;
        }
        bounds[g] = lo;
    }
    int i = blockIdx.x * blockDim.x + threadIdx.x;
    int lane = threadIdx.x & 63;
    int v = (i < N_NODES) ? deg[i] : 0;
    int incl = v;
    for (int o = 1; o < 64; o <<= 1) {
        int t = __shfl_up(incl, o);
        if (lane >= o) incl += t;
    }
    int wtot = __shfl(incl, 63);
    int base = 0;
    if (lane == 0) base = atomicAdd(total, wtot);
    base = __shfl(base, 0);
    if (i < N_NODES) {
        offs[i] = base + incl - v;
        atomicAdd(&lh[63 - min(v, 63)], 1);  // LDS atomic, block-local; LPT flip
    }
    __syncthreads();
    if (threadIdx.x < 64) bh[blockIdx.x * 64 + threadIdx.x] = lh[threadIdx.x];
}

// single block: bucket totals -> exclusive bucket scan -> per-block bucket bases
__global__ __launch_bounds__(256) void k_pscan(const int* __restrict__ bh, int* __restrict__ bb) {
    __shared__ int partial[4][64];
    __shared__ int bbase[64];
    const int tid = threadIdx.x;
    const int b = tid & 63, q = tid >> 6;
    const int per = (NB_SCAN + 3) / 4;
    const int k0 = q * per, k1 = min(k0 + per, NB_SCAN);
    int s = 0;
    for (int k = k0; k < k1; ++k) s += bh[k * 64 + b];
    partial[q][b] = s;
    __syncthreads();
    if (tid < 64) {
        int tot = partial[0][tid] + partial[1][tid] + partial[2][tid] + partial[3][tid];
        int incl = tot;
        for (int o = 1; o < 64; o <<= 1) {
            int t2 = __shfl_up(incl, o);
            if (tid >= o) incl += t2;
        }
        bbase[tid] = incl - tot;
    }
    __syncthreads();
    int run = bbase[b];
    for (int q2 = 0; q2 < q; ++q2) run += partial[q2][b];
    for (int k = k0; k < k1; ++k) {
        bb[k * 64 + b] = run;
        run += bh[k * 64 + b];
    }
}

// scatter node ids into degree-sorted (descending) order
__global__ __launch_bounds__(256) void k_perm(const int* __restrict__ deg,
                                              const int* __restrict__ bb,
                                              int* __restrict__ perm) {
    __shared__ int lcnt[64];
    if (threadIdx.x < 64) lcnt[threadIdx.x] = 0;
    __syncthreads();
    int i = blockIdx.x * 256 + threadIdx.x;
    if (i < N_NODES) {
        int b = 63 - min(deg[i], 63);  // LPT flip
        int r = atomicAdd(&lcnt[b], 1);
        perm[bb[blockIdx.x * 64 + b] + r] = i;
    }
}

__global__ void k_fill(const int* __restrict__ ei, const int* __restrict__ offs,
                       int* __restrict__ cur, int* __restrict__ csr_src) {
    int e = blockIdx.x * blockDim.x + threadIdx.x;
    if (e < N_EDGES) {
        int d = ei[N_EDGES + e];
        int pos = offs[d] + atomicAdd(&cur[d], 1);
        csr_src[pos] = ei[e];
    }
}

// ---------------- MFMA GEMM + fused attention dots (layer 1 only) ----------------
template <int K, int N, int HEADS, bool AF32>
__global__ __launch_bounds__(256) void k_mgemm(const void* __restrict__ Ap,
                                               const unsigned short* __restrict__ Bt,
                                               const float* __restrict__ asrc,
                                               const float* __restrict__ adst,
                                               unsigned short* __restrict__ out,
                                               float* __restrict__ es,
                                               float* __restrict__ ed, int rows) {
    constexpr int LDP = K + 8;
    __shared__ unsigned short As[64 * LDP];
    const int tid = threadIdx.x;
    const int r0 = blockIdx.x * 64;
    if (AF32) {
        const float* A = (const float*)Ap;
        for (int i = tid; i < 16 * K; i += 256) {
            int r = i / (K / 4), c4 = i % (K / 4);
            int row = r0 + r;
            float4 v = (row < rows) ? *(const float4*)&A[(size_t)row * K + c4 * 4]
                                    : make_float4(0.f, 0.f, 0.f, 0.f);
            ushort4 u;
            u.x = f2b(v.x); u.y = f2b(v.y); u.z = f2b(v.z); u.w = f2b(v.w);
            *(ushort4*)&As[r * LDP + c4 * 4] = u;
        }
    } else {
        const unsigned short* A = (const unsigned short*)Ap;
        for (int i = tid; i < 8 * K; i += 256) {
            int r = i / (K / 8), c8 = i % (K / 8);
            int row = r0 + r;
            uint4 v;
            if (row < rows) v = *(const uint4*)&A[(size_t)row * K + c8 * 8];
            else { v.x = v.y = v.z = v.w = 0; }
            *(uint4*)&As[r * LDP + c8 * 8] = v;
        }
    }
    __syncthreads();
    const int w = tid >> 6, lane = tid & 63;
    const int quad = lane >> 4, l16 = lane & 15;
    const int gr0 = r0 + w * 16 + quad * 4;
    bf16x8 afrag[K / 32];
#pragma unroll
    for (int kk = 0; kk < K / 32; ++kk)
        afrag[kk] = *(const bf16x8*)&As[(w * 16 + l16) * LDP + kk * 32 + quad * 8];
    float sacc[4] = {0.f, 0.f, 0.f, 0.f};
    float dacc[4] = {0.f, 0.f, 0.f, 0.f};
#pragma unroll 1
    for (int ct = 0; ct < N / 16; ++ct) {
        floatx4 acc = {0.f, 0.f, 0.f, 0.f};
#pragma unroll
        for (int kk = 0; kk < K / 32; ++kk) {
            const bf16x8 bfrag =
                *(const bf16x8*)&Bt[(size_t)(ct * 16 + l16) * K + kk * 32 + quad * 8];
            acc = __builtin_amdgcn_mfma_f32_16x16x32_bf16(afrag[kk], bfrag, acc, 0, 0, 0);
        }
        const int gc = ct * 16 + l16;
        const int hh = gc >> 6;
        const int f = gc & 63;
        const float as = asrc[hh * 64 + f];
        const float ad = adst[hh * 64 + f];
#pragma unroll
        for (int rg = 0; rg < 4; ++rg) {
            sacc[rg] = fmaf(acc[rg], as, sacc[rg]);
            dacc[rg] = fmaf(acc[rg], ad, dacc[rg]);
        }
#pragma unroll
        for (int rg = 0; rg < 4; ++rg) {
            int gr = gr0 + rg;
            if (gr < rows) out[(size_t)gr * N + gc] = f2b(acc[rg]);
        }
        if ((ct & 3) == 3) {
#pragma unroll
            for (int rg = 0; rg < 4; ++rg) {
                float s = sacc[rg], d = dacc[rg];
                for (int o = 1; o < 16; o <<= 1) {
                    s += __shfl_xor(s, o);
                    d += __shfl_xor(d, o);
                }
                if (l16 == 0) {
                    int gr = gr0 + rg;
                    if (gr < rows) {
                        es[(size_t)gr * HEADS + hh] = s;
                        ed[(size_t)gr * HEADS + hh] = d;
                    }
                }
                sacc[rg] = 0.f;
                dacc[rg] = 0.f;
            }
        }
    }
}

// ---------------- GAT layer 1 + fused layer-2 GEMM/dots ----------------
// ONE 16-lane group per dst node (grid exact: 3125*16 = 50000). After aggregation,
// the group holds all 256 cols of x1[n]: round-trip bf16 through LDS, then in-group
// GEMM with W2 (global, L1/L2-hot) -> xW2[n] (bf16) + es2/ed2[n] dots. This deletes
// the separate mgemm<256,64> dispatch and the x1 materialization entirely.
__global__ __launch_bounds__(256) void k_gat1(
    const unsigned short* __restrict__ xW, const float* __restrict__ es, const float* __restrict__ ed,
    const int* __restrict__ offs, const int* __restrict__ deg, const int* __restrict__ csr,
    const int* __restrict__ perm, const float* __restrict__ bias,
    const unsigned short* __restrict__ W2b, const float* __restrict__ asrc2,
    const float* __restrict__ adst2, unsigned short* __restrict__ xW2,
    float* __restrict__ es2, float* __restrict__ ed2) {
    __shared__ float ps[4][4 * 68];
    __shared__ int sbuf[4][64];
    __shared__ unsigned short x1buf[4][1024];  // [wave][grp*256 + c]
    const int wv = threadIdx.x >> 6;
    const int lane = threadIdx.x & 63;
    const int grp = lane >> 4, t = lane & 15;
    const int h = t >> 2;
    const int pidx = blockIdx.x * 16 + wv * 4 + grp;
    const int n = perm[pidx];
    const int off = offs[n];
    const int dg = deg[n];
    const float4 edv = *(const float4*)&ed[n * 4];
    const int cb = t * 16;

    float acc[16];
#pragma unroll
    for (int k = 0; k < 16; ++k) acc[k] = 0.f;
    float dsum = 0.f;

    for (int base = 0; base < dg; base += 16) {
        const int idx = base + t;
        int s_l = 0;
        float p0 = 0.f, p1 = 0.f, p2 = 0.f, p3 = 0.f;
        if (idx < dg) {
            s_l = csr[off + idx];
            const float4 ev = *(const float4*)&es[s_l * 4];
            p0 = __expf(lrelu(ev.x + edv.x));
            p1 = __expf(lrelu(ev.y + edv.y));
            p2 = __expf(lrelu(ev.z + edv.z));
            p3 = __expf(lrelu(ev.w + edv.w));
        }
        *(float4*)&ps[wv][grp * 68 + t * 4] = make_float4(p0, p1, p2, p3);
        sbuf[wv][grp * 16 + t] = s_l;
        const int cnt = min(16, dg - base);
        const int cntR = (cnt + 1) & ~1;
        for (int j = 0; j < cntR; j += 2) {
            const float pa = ps[wv][grp * 68 + (j + 0) * 4 + h];
            const float pb = ps[wv][grp * 68 + (j + 1) * 4 + h];
            const int sa = sbuf[wv][grp * 16 + j + 0];
            const int sb = sbuf[wv][grp * 16 + j + 1];
            const uint4 a0 = *(const uint4*)&xW[(size_t)sa * 256 + cb];
            const uint4 a1 = *(const uint4*)&xW[(size_t)sa * 256 + cb + 8];
            const uint4 b0 = *(const uint4*)&xW[(size_t)sb * 256 + cb];
            const uint4 b1 = *(const uint4*)&xW[(size_t)sb * 256 + cb + 8];
            dsum += pa + pb;
            acc[0]  = fmaf(pa, blo(a0.x), acc[0]);
            acc[1]  = fmaf(pa, bhi(a0.x), acc[1]);
            acc[2]  = fmaf(pa, blo(a0.y), acc[2]);
            acc[3]  = fmaf(pa, bhi(a0.y), acc[3]);
            acc[4]  = fmaf(pa, blo(a0.z), acc[4]);
            acc[5]  = fmaf(pa, bhi(a0.z), acc[5]);
            acc[6]  = fmaf(pa, blo(a0.w), acc[6]);
            acc[7]  = fmaf(pa, bhi(a0.w), acc[7]);
            acc[8]  = fmaf(pa, blo(a1.x), acc[8]);
            acc[9]  = fmaf(pa, bhi(a1.x), acc[9]);
            acc[10] = fmaf(pa, blo(a1.y), acc[10]);
            acc[11] = fmaf(pa, bhi(a1.y), acc[11]);
            acc[12] = fmaf(pa, blo(a1.z), acc[12]);
            acc[13] = fmaf(pa, bhi(a1.z), acc[13]);
            acc[14] = fmaf(pa, blo(a1.w), acc[14]);
            acc[15] = fmaf(pa, bhi(a1.w), acc[15]);
            acc[0]  = fmaf(pb, blo(b0.x), acc[0]);
            acc[1]  = fmaf(pb, bhi(b0.x), acc[1]);
            acc[2]  = fmaf(pb, blo(b0.y), acc[2]);
            acc[3]  = fmaf(pb, bhi(b0.y), acc[3]);
            acc[4]  = fmaf(pb, blo(b0.z), acc[4]);
            acc[5]  = fmaf(pb, bhi(b0.z), acc[5]);
            acc[6]  = fmaf(pb, blo(b0.w), acc[6]);
            acc[7]  = fmaf(pb, bhi(b0.w), acc[7]);
            acc[8]  = fmaf(pb, blo(b1.x), acc[8]);
            acc[9]  = fmaf(pb, bhi(b1.x), acc[9]);
            acc[10] = fmaf(pb, blo(b1.y), acc[10]);
            acc[11] = fmaf(pb, bhi(b1.y), acc[11]);
            acc[12] = fmaf(pb, blo(b1.z), acc[12]);
            acc[13] = fmaf(pb, bhi(b1.z), acc[13]);
            acc[14] = fmaf(pb, blo(b1.w), acc[14]);
            acc[15] = fmaf(pb, bhi(b1.w), acc[15]);
        }
    }
    const float inv = 1.0f / fmaxf(dsum, 1e-16f);
    unsigned short* x1s = &x1buf[wv][grp * 256];
#pragma unroll
    for (int k4 = 0; k4 < 16; k4 += 4) {
        const int c = cb + k4;
        const float4 bv = *(const float4*)&bias[c];
        ushort4 o4;
        o4.x = f2b(fmaxf(fmaf(acc[k4 + 0], inv, bv.x), 0.f));
        o4.y = f2b(fmaxf(fmaf(acc[k4 + 1], inv, bv.y), 0.f));
        o4.z = f2b(fmaxf(fmaf(acc[k4 + 2], inv, bv.z), 0.f));
        o4.w = f2b(fmaxf(fmaf(acc[k4 + 3], inv, bv.w), 0.f));
        *(ushort4*)&x1s[c] = o4;
    }
    // wave-synchronous LDS round-trip (group within one wave, no barrier)
    // in-group GEMM: x1[n] (256) @ W2 (256x64) -> 4 cols per lane
    const int c0 = t * 4;
    float og0 = 0.f, og1 = 0.f, og2 = 0.f, og3 = 0.f;
    for (int k = 0; k < 256; k += 2) {
        const unsigned int xp = *(const unsigned int*)&x1s[k];
        const float xk0 = blo(xp), xk1 = bhi(xp);
        const ushort4 w0 = *(const ushort4*)&W2b[k * 64 + c0];
        const ushort4 w1 = *(const ushort4*)&W2b[(k + 1) * 64 + c0];
        og0 = fmaf(xk0, b2f(w0.x), og0);
        og1 = fmaf(xk0, b2f(w0.y), og1);
        og2 = fmaf(xk0, b2f(w0.z), og2);
        og3 = fmaf(xk0, b2f(w0.w), og3);
        og0 = fmaf(xk1, b2f(w1.x), og0);
        og1 = fmaf(xk1, b2f(w1.y), og1);
        og2 = fmaf(xk1, b2f(w1.z), og2);
        og3 = fmaf(xk1, b2f(w1.w), og3);
    }
    const float4 a2s = *(const float4*)&asrc2[c0];
    const float4 a2d = *(const float4*)&adst2[c0];
    float s2 = og0 * a2s.x + og1 * a2s.y + og2 * a2s.z + og3 * a2s.w;
    float d2 = og0 * a2d.x + og1 * a2d.y + og2 * a2d.z + og3 * a2d.w;
    for (int o = 1; o < 16; o <<= 1) {
        s2 += __shfl_xor(s2, o);
        d2 += __shfl_xor(d2, o);
    }
    if (t == 0) { es2[n] = s2; ed2[n] = d2; }
    ushort4 xw;
    xw.x = f2b(og0); xw.y = f2b(og1); xw.z = f2b(og2); xw.w = f2b(og3);
    *(ushort4*)&xW2[(size_t)n * 64 + c0] = xw;
}

// ---------------- GAT layers 2-4 + fused next-layer GEMM/dots ----------------
// ONE 8-lane group per node. NEXT: epilogue computes xW_next[n] = bf16(h[n]) @ Wn
// (64x64, global L1-hot) + es/ed dots for the next layer.
template <bool RES, bool NEXT>
__global__ __launch_bounds__(256) void k_gatL(
    const unsigned short* __restrict__ xW, const float* __restrict__ es, const float* __restrict__ ed,
    const int* __restrict__ offs, const int* __restrict__ deg, const int* __restrict__ csr,
    const int* __restrict__ perm, const float* __restrict__ bias, const float* __restrict__ gam,
    const float* __restrict__ bet, float* __restrict__ h,
    const unsigned short* __restrict__ Wn, const float* __restrict__ asn,
    const float* __restrict__ adn, unsigned short* __restrict__ xwn,
    float* __restrict__ esn, float* __restrict__ edn) {
    __shared__ float ps[4][64];
    __shared__ int sbuf[4][64];
    __shared__ unsigned short hbuf[4][512];  // [wave][grp*64 + c]
    const int wv = threadIdx.x >> 6;
    const int lane = threadIdx.x & 63;
    const int grp = lane >> 3, t = lane & 7;
    const int pidx = blockIdx.x * 32 + wv * 8 + grp;
    if (pidx >= N_NODES) return;
    const int n = perm[pidx];
    const int off = offs[n];
    const int dg = deg[n];
    const float edv = ed[n];
    const int cb = t * 8;

    float acc[8];
#pragma unroll
    for (int k = 0; k < 8; ++k) acc[k] = 0.f;
    float dsum = 0.f;

    for (int base = 0; base < dg; base += 8) {
        const int idx = base + t;
        int s_l = 0;
        float p_l = 0.f;
        if (idx < dg) {
            s_l = csr[off + idx];
            p_l = __expf(lrelu(es[s_l] + edv));
        }
        ps[wv][grp * 8 + t] = p_l;
        sbuf[wv][grp * 8 + t] = s_l;
        const int cnt = min(8, dg - base);
        const int cntR = (cnt + 1) & ~1;
        for (int j = 0; j < cntR; j += 2) {
            const float pa = ps[wv][grp * 8 + j];
            const float pb = ps[wv][grp * 8 + j + 1];
            const int sa = sbuf[wv][grp * 8 + j];
            const int sb = sbuf[wv][grp * 8 + j + 1];
            const uint4 a = *(const uint4*)&xW[(size_t)sa * 64 + cb];
            const uint4 b = *(const uint4*)&xW[(size_t)sb * 64 + cb];
            dsum += pa + pb;
            acc[0] = fmaf(pa, blo(a.x), acc[0]);
            acc[1] = fmaf(pa, bhi(a.x), acc[1]);
            acc[2] = fmaf(pa, blo(a.y), acc[2]);
            acc[3] = fmaf(pa, bhi(a.y), acc[3]);
            acc[4] = fmaf(pa, blo(a.z), acc[4]);
            acc[5] = fmaf(pa, bhi(a.z), acc[5]);
            acc[6] = fmaf(pa, blo(a.w), acc[6]);
            acc[7] = fmaf(pa, bhi(a.w), acc[7]);
            acc[0] = fmaf(pb, blo(b.x), acc[0]);
            acc[1] = fmaf(pb, bhi(b.x), acc[1]);
            acc[2] = fmaf(pb, blo(b.y), acc[2]);
            acc[3] = fmaf(pb, bhi(b.y), acc[3]);
            acc[4] = fmaf(pb, blo(b.z), acc[4]);
            acc[5] = fmaf(pb, bhi(b.z), acc[5]);
            acc[6] = fmaf(pb, blo(b.w), acc[6]);
            acc[7] = fmaf(pb, bhi(b.w), acc[7]);
        }
    }
    const float inv = 1.0f / fmaxf(dsum, 1e-16f);
    float hn[8];
#pragma unroll
    for (int k = 0; k < 8; ++k) {
        const int c = cb + k;
        const float y = fmaf(acc[k], inv, bias[c]);
        const float z = fmaxf(fmaf(gam[c] * y, BN_RSQ, bet[c]), 0.f);
        hn[k] = RES ? h[(size_t)n * 64 + c] + z : z;
    }
    *(float4*)&h[(size_t)n * 64 + cb] = make_float4(hn[0], hn[1], hn[2], hn[3]);
    *(float4*)&h[(size_t)n * 64 + cb + 4] = make_float4(hn[4], hn[5], hn[6], hn[7]);
    if (NEXT) {
        unsigned short* hbl = &hbuf[wv][grp * 64];
        ushort4 u0, u1;
        u0.x = f2b(hn[0]); u0.y = f2b(hn[1]); u0.z = f2b(hn[2]); u0.w = f2b(hn[3]);
        u1.x = f2b(hn[4]); u1.y = f2b(hn[5]); u1.z = f2b(hn[6]); u1.w = f2b(hn[7]);
        *(ushort4*)&hbl[cb] = u0;
        *(ushort4*)&hbl[cb + 4] = u1;
        // in-group GEMM: bf16(h[n]) (64) @ Wn (64x64) -> 8 cols per lane
        float og[8];
#pragma unroll
        for (int k = 0; k < 8; ++k) og[k] = 0.f;
        for (int k = 0; k < 64; k += 2) {
            const unsigned int xp = *(const unsigned int*)&hbl[k];
            const float xk0 = blo(xp), xk1 = bhi(xp);
            const uint4 w0 = *(const uint4*)&Wn[k * 64 + cb];
            const uint4 w1 = *(const uint4*)&Wn[(k + 1) * 64 + cb];
            og[0] = fmaf(xk0, blo(w0.x), og[0]);
            og[1] = fmaf(xk0, bhi(w0.x), og[1]);
            og[2] = fmaf(xk0, blo(w0.y), og[2]);
            og[3] = fmaf(xk0, bhi(w0.y), og[3]);
            og[4] = fmaf(xk0, blo(w0.z), og[4]);
            og[5] = fmaf(xk0, bhi(w0.z), og[5]);
            og[6] = fmaf(xk0, blo(w0.w), og[6]);
            og[7] = fmaf(xk0, bhi(w0.w), og[7]);
            og[0] = fmaf(xk1, blo(w1.x), og[0]);
            og[1] = fmaf(xk1, bhi(w1.x), og[1]);
            og[2] = fmaf(xk1, blo(w1.y), og[2]);
            og[3] = fmaf(xk1, bhi(w1.y), og[3]);
            og[4] = fmaf(xk1, blo(w1.z), og[4]);
            og[5] = fmaf(xk1, bhi(w1.z), og[5]);
            og[6] = fmaf(xk1, blo(w1.w), og[6]);
            og[7] = fmaf(xk1, bhi(w1.w), og[7]);
        }
        float s = 0.f, d = 0.f;
#pragma unroll
        for (int kk = 0; kk < 8; kk += 4) {
            const float4 asv = *(const float4*)&asn[cb + kk];
            const float4 adv = *(const float4*)&adn[cb + kk];
            s += og[kk] * asv.x + og[kk + 1] * asv.y + og[kk + 2] * asv.z + og[kk + 3] * asv.w;
            d += og[kk] * adv.x + og[kk + 1] * adv.y + og[kk + 2] * adv.z + og[kk + 3] * adv.w;
        }
        for (int o = 1; o < 8; o <<= 1) {
            s += __shfl_xor(s, o);
            d += __shfl_xor(d, o);
        }
        if (t == 0) { esn[n] = s; edn[n] = d; }
        ushort4 x0, x1v;
        x0.x = f2b(og[0]); x0.y = f2b(og[1]); x0.z = f2b(og[2]); x0.w = f2b(og[3]);
        x1v.x = f2b(og[4]); x1v.y = f2b(og[5]); x1v.z = f2b(og[6]); x1v.w = f2b(og[7]);
        *(ushort4*)&xwn[(size_t)n * 64 + cb] = x0;
        *(ushort4*)&xwn[(size_t)n * 64 + cb + 4] = x1v;
    }
}

// ---------------- mean pool: one block per graph, contiguous node range, no atomics ----------------
__global__ __launch_bounds__(256) void k_pool2(const float* __restrict__ h,
                                               const int* __restrict__ bounds,
                                               float* __restrict__ hp) {
    __shared__ float part[4][64];
    const int g = blockIdx.x;
    const int lane = threadIdx.x & 63;
    const int wid = threadIdx.x >> 6;
    const int s = bounds[g], e = bounds[g + 1];
    float acc = 0.f;
    for (int n = s + wid; n < e; n += 4) acc += h[n * 64 + lane];
    part[wid][lane] = acc;
    __syncthreads();
    if (wid == 0) {
        float v = part[0][lane] + part[1][lane] + part[2][lane] + part[3][lane];
        hp[g * 64 + lane] = v / fmaxf((float)(e - s), 1.0f);
    }
}

// ---------------- MLP head, single block (hp already mean-pooled) ----------------
__global__ __launch_bounds__(256) void k_head(const float* __restrict__ hpg,
                                              const float* __restrict__ Wh1,
                                              const float* __restrict__ bh1,
                                              const float* __restrict__ Wh2,
                                              const float* __restrict__ bh2,
                                              float* __restrict__ out) {
    __shared__ float hp[64 * 64];
    __shared__ float t1[64 * 128];
    const int tid = threadIdx.x;
    for (int i = tid; i < 64 * 64; i += 256) hp[i] = hpg[i];
    __syncthreads();
    for (int i = tid; i < 64 * 128; i += 256) {
        int g = i >> 7, j = i & 127;
        float s = bh1[j];
        for (int k = 0; k < 64; ++k) s = fmaf(hp[g * 64 + k], Wh1[k * 128 + j], s);
        t1[i] = fmaxf(s, 0.f);
    }
    __syncthreads();
    for (int i = tid; i < 640; i += 256) {
        int g = i / 10, j = i - g * 10;
        float s = bh2[j];
        for (int k = 0; k < 128; ++k) s = fmaf(t1[g * 128 + k], Wh2[k * 10 + j], s);
        out[i] = s;
    }
}

extern "C" void kernel_launch(void* const* d_in, const int* in_sizes, int n_in,
                              void* d_out, int out_size, void* d_ws, size_t ws_size,
                              hipStream_t stream) {
    const float* x = (const float*)d_in[1];
    const int* ei = (const int*)d_in[2];
    const int* batch = (const int*)d_in[3];
    const float* W1 = (const float*)d_in[4];
    const float* a_src1 = (const float*)d_in[5];
    const float* a_dst1 = (const float*)d_in[6];
    const float* b1 = (const float*)d_in[7];
    const float* W2 = (const float*)d_in[8];
    const float* a_src2 = (const float*)d_in[9];
    const float* a_dst2 = (const float*)d_in[10];
    const float* b2 = (const float*)d_in[11];
    const float* g2 = (const float*)d_in[12];
    const float* be2 = (const float*)d_in[13];
    const float* W3 = (const float*)d_in[14];
    const float* a_src3 = (const float*)d_in[15];
    const float* a_dst3 = (const float*)d_in[16];
    const float* b3 = (const float*)d_in[17];
    const float* g3 = (const float*)d_in[18];
    const float* be3 = (const float*)d_in[19];
    const float* W4 = (const float*)d_in[20];
    const float* a_src4 = (const float*)d_in[21];
    const float* a_dst4 = (const float*)d_in[22];
    const float* b4 = (const float*)d_in[23];
    const float* g4 = (const float*)d_in[24];
    const float* be4 = (const float*)d_in[25];
    const float* Wh1 = (const float*)d_in[26];
    const float* bh1 = (const float*)d_in[27];
    const float* Wh2 = (const float*)d_in[28];
    const float* bh2 = (const float*)d_in[29];
    float* out = (float*)d_out;

    // workspace layout
    char* p = (char*)d_ws;
    auto alloc = [&](size_t bytes) {
        void* r = (void*)p;
        p += (bytes + 255) & ~(size_t)255;
        return r;
    };
    unsigned short* bufA = (unsigned short*)alloc((size_t)N_NODES * 256 * 2);  // xW1; then xW3
    unsigned short* bufB = (unsigned short*)alloc((size_t)N_NODES * 64 * 2);   // xW2; then xW4
    float* h = (float*)alloc((size_t)N_NODES * 64 * 4);                        // h fp32
    float* es1 = (float*)alloc((size_t)N_NODES * 4 * 4);
    float* ed1 = (float*)alloc((size_t)N_NODES * 4 * 4);
    float* esA = (float*)alloc((size_t)N_NODES * 4);  // layer2 scores; then layer4
    float* edA = (float*)alloc((size_t)N_NODES * 4);
    float* esB = (float*)alloc((size_t)N_NODES * 4);  // layer3 scores
    float* edB = (float*)alloc((size_t)N_NODES * 4);
    int* offs = (int*)alloc((size_t)N_NODES * 4);
    int* csr = (int*)alloc((size_t)N_EDGES * 4);
    int* perm = (int*)alloc((size_t)N_NODES * 4);
    int* bounds = (int*)alloc((size_t)(N_GRAPHS + 1) * 4);
    int* bh_hist = (int*)alloc((size_t)NB_SCAN * 64 * 4);
    int* bb = (int*)alloc((size_t)NB_SCAN * 64 * 4);
    float* hpool = (float*)alloc((size_t)N_GRAPHS * 64 * 4);
    unsigned short* Wt1 = (unsigned short*)alloc((size_t)128 * 256 * 2);
    unsigned short* W2b = (unsigned short*)alloc((size_t)256 * 64 * 2);
    unsigned short* W3b = (unsigned short*)alloc((size_t)64 * 64 * 2);
    unsigned short* W4b = (unsigned short*)alloc((size_t)64 * 64 * 2);
    char* z0 = p;  // everything below gets zeroed each call
    int* deg = (int*)alloc((size_t)N_NODES * 4);
    int* cur = (int*)alloc((size_t)N_NODES * 4);
    int* total = (int*)alloc(256);
    size_t zbytes = (size_t)(p - z0);
    hipMemsetAsync(z0, 0, zbytes, stream);

    const int edgeBlocks = (N_EDGES + 255) / 256;
    const int mgemmBlocks = (N_NODES + 63) / 64;
    const int gat1Blocks = (N_NODES + 15) / 16;  // 3125 exact: every group active
    const int gatLBlocks = (N_NODES + 31) / 32;

    // fused prep: degree count + weight bf16 conversion
    k_prep<<<edgeBlocks, 256, 0, stream>>>(ei, deg, W1, W2, W3, W4, Wt1, W2b, W3b, W4b);

    // CSR build + LPT (descending-degree) permutation + graph bounds
    k_offs<<<NB_SCAN, 256, 0, stream>>>(deg, offs, total, batch, bounds, bh_hist);
    k_pscan<<<1, 256, 0, stream>>>(bh_hist, bb);
    k_perm<<<NB_SCAN, 256, 0, stream>>>(deg, bb, perm);
    k_fill<<<edgeBlocks, 256, 0, stream>>>(ei, offs, cur, csr);

    // layer 1 GEMM (MFMA) -> xW1 + es1/ed1
    k_mgemm<128, 256, 4, true><<<mgemmBlocks, 256, 0, stream>>>(x, Wt1, a_src1, a_dst1,
                                                                bufA, es1, ed1, N_NODES);
    // layer-1 GAT + fused layer-2 GEMM/dots -> xW2 + es2/ed2
    k_gat1<<<gat1Blocks, 256, 0, stream>>>(bufA, es1, ed1, offs, deg, csr, perm, b1,
                                           W2b, a_src2, a_dst2, bufB, esA, edA);
    // layer 2 GAT + fused layer-3 GEMM/dots -> h, xW3 + es3/ed3
    k_gatL<false, true><<<gatLBlocks, 256, 0, stream>>>(bufB, esA, edA, offs, deg, csr, perm,
                                                        b2, g2, be2, h, W3b, a_src3, a_dst3,
                                                        bufA, esB, edB);
    // layer 3 GAT + fused layer-4 GEMM/dots -> h, xW4 + es4/ed4
    k_gatL<true, true><<<gatLBlocks, 256, 0, stream>>>(bufA, esB, edB, offs, deg, csr, perm,
                                                       b3, g3, be3, h, W4b, a_src4, a_dst4,
                                                       bufB, esA, edA);
    // layer 4 GAT (no next layer)
    k_gatL<true, false><<<gatLBlocks, 256, 0, stream>>>(bufB, esA, edA, offs, deg, csr, perm,
                                                        b4, g4, be4, h, (const unsigned short*)nullptr,
                                                        (const float*)nullptr, (const float*)nullptr,
                                                        (unsigned short*)nullptr,
                                                        (float*)nullptr, (float*)nullptr);

    // pool + head (batch sorted -> contiguous ranges, no atomics)
    k_pool2<<<N_GRAPHS, 256, 0, stream>>>(h, bounds, hpool);
    k_head<<<1, 256, 0, stream>>>(hpool, Wh1, bh1, Wh2, bh2, out);
}

// Round 12
// 516.104 us; speedup vs baseline: 1.1184x; 1.1184x over previous
//
#include <hip/hip_runtime.h>

#define N_NODES 50000
#define N_EDGES 800000
#define N_GRAPHS 64
#define NEG_SLOPE 0.2f
// 1/sqrt(1 + 1e-5), BN eval-mode scale
#define BN_RSQ 0.9999950000374997f
#define NB_SCAN ((N_NODES + 255) / 256)  // 196 blocks in the node-space scan

typedef __bf16 bf16x8 __attribute__((ext_vector_type(8)));
typedef float floatx4 __attribute__((ext_vector_type(4)));

__device__ __forceinline__ float lrelu(float v) { return v > 0.0f ? v : NEG_SLOPE * v; }

// bf16 <-> f32 (round-to-nearest-even)
__device__ __forceinline__ float b2f(unsigned short u) {
    return __uint_as_float(((unsigned int)u) << 16);
}
__device__ __forceinline__ unsigned short f2b(float f) {
    unsigned int u = __float_as_uint(f);
    return (unsigned short)((u + 0x7fffu + ((u >> 16) & 1u)) >> 16);
}
// unpack 2 bf16 from one dword (1 instr each: shl / and)
__device__ __forceinline__ float blo(unsigned int d) { return __uint_as_float(d << 16); }
__device__ __forceinline__ float bhi(unsigned int d) { return __uint_as_float(d & 0xffff0000u); }

// ---------------- fused prep: degree count + weight bf16 transpose (all layers) ----------------
// Wt[n*K+k] = bf16(W[k*N+n]) — MFMA B-fragment layout for k_mgemm.
__global__ void k_prep(const int* __restrict__ ei, int* __restrict__ deg,
                       const float* __restrict__ W1, const float* __restrict__ W2,
                       const float* __restrict__ W3, const float* __restrict__ W4,
                       unsigned short* __restrict__ Wt1, unsigned short* __restrict__ Wt2,
                       unsigned short* __restrict__ Wt3, unsigned short* __restrict__ Wt4) {
    int i = blockIdx.x * 256 + threadIdx.x;
    if (i < 32768) {  // W1: 128x256
        int k = i >> 8, n = i & 255;
        Wt1[n * 128 + k] = f2b(W1[i]);
    } else if (i < 49152) {  // W2: 256x64
        int j = i - 32768;
        int k = j >> 6, n = j & 63;
        Wt2[n * 256 + k] = f2b(W2[j]);
    } else if (i < 53248) {  // W3: 64x64
        int j = i - 49152;
        int k = j >> 6, n = j & 63;
        Wt3[n * 64 + k] = f2b(W3[j]);
    } else if (i < 57344) {  // W4: 64x64
        int j = i - 53248;
        int k = j >> 6, n = j & 63;
        Wt4[n * 64 + k] = f2b(W4[j]);
    }
    if (i < N_EDGES) atomicAdd(&deg[ei[N_EDGES + i]], 1);
}

// offsets via wave shuffle-scan + one atomic per wave; per-block degree histogram
// (LPT: bucket = 63 - min(deg,63) -> descending-degree sort, long blocks first);
// graph bounds (batch sorted).
__global__ __launch_bounds__(256) void k_offs(const int* __restrict__ deg, int* __restrict__ offs,
                                              int* __restrict__ total, const int* __restrict__ batch,
                                              int* __restrict__ bounds, int* __restrict__ bh) {
    __shared__ int lh[64];
    if (threadIdx.x < 64) lh[threadIdx.x] = 0;
    __syncthreads();
    if (blockIdx.x == 0 && threadIdx.x <= N_GRAPHS) {
        int g = threadIdx.x;
        int lo = 0, hi = N_NODES;
        while (lo < hi) {
            int mid = (lo + hi) >> 1;
            if (batch[mid] < g) lo = mid + 1; else hi = mid;
        }
        bounds[g] = lo;
    }
    int i = blockIdx.x * blockDim.x + threadIdx.x;
    int lane = threadIdx.x & 63;
    int v = (i < N_NODES) ? deg[i] : 0;
    int incl = v;
    for (int o = 1; o < 64; o <<= 1) {
        int t = __shfl_up(incl, o);
        if (lane >= o) incl += t;
    }
    int wtot = __shfl(incl, 63);
    int base = 0;
    if (lane == 0) base = atomicAdd(total, wtot);
    base = __shfl(base, 0);
    if (i < N_NODES) {
        offs[i] = base + incl - v;
        atomicAdd(&lh[63 - min(v, 63)], 1);  // LDS atomic, block-local; LPT flip
    }
    __syncthreads();
    if (threadIdx.x < 64) bh[blockIdx.x * 64 + threadIdx.x] = lh[threadIdx.x];
}

// single block: bucket totals -> exclusive bucket scan -> per-block bucket bases
__global__ __launch_bounds__(256) void k_pscan(const int* __restrict__ bh, int* __restrict__ bb) {
    __shared__ int partial[4][64];
    __shared__ int bbase[64];
    const int tid = threadIdx.x;
    const int b = tid & 63, q = tid >> 6;
    const int per = (NB_SCAN + 3) / 4;
    const int k0 = q * per, k1 = min(k0 + per, NB_SCAN);
    int s = 0;
    for (int k = k0; k < k1; ++k) s += bh[k * 64 + b];
    partial[q][b] = s;
    __syncthreads();
    if (tid < 64) {
        int tot = partial[0][tid] + partial[1][tid] + partial[2][tid] + partial[3][tid];
        int incl = tot;
        for (int o = 1; o < 64; o <<= 1) {
            int t2 = __shfl_up(incl, o);
            if (tid >= o) incl += t2;
        }
        bbase[tid] = incl - tot;
    }
    __syncthreads();
    int run = bbase[b];
    for (int q2 = 0; q2 < q; ++q2) run += partial[q2][b];
    for (int k = k0; k < k1; ++k) {
        bb[k * 64 + b] = run;
        run += bh[k * 64 + b];
    }
}

// merged: CSR fill (all blocks, edge-space) + degree-sort scatter (first NB_SCAN blocks)
__global__ __launch_bounds__(256) void k_fillperm(const int* __restrict__ ei,
                                                  const int* __restrict__ offs,
                                                  int* __restrict__ cur, int* __restrict__ csr_src,
                                                  const int* __restrict__ deg,
                                                  const int* __restrict__ bb,
                                                  int* __restrict__ perm) {
    __shared__ int lcnt[64];
    if (blockIdx.x < NB_SCAN) {  // block-uniform branch: barrier is safe
        if (threadIdx.x < 64) lcnt[threadIdx.x] = 0;
        __syncthreads();
        int i = blockIdx.x * 256 + threadIdx.x;
        if (i < N_NODES) {
            int b = 63 - min(deg[i], 63);  // LPT flip
            int r = atomicAdd(&lcnt[b], 1);
            perm[bb[blockIdx.x * 64 + b] + r] = i;
        }
    }
    int e = blockIdx.x * 256 + threadIdx.x;
    if (e < N_EDGES) {
        int d = ei[N_EDGES + e];
        int pos = offs[d] + atomicAdd(&cur[d], 1);
        csr_src[pos] = ei[e];
    }
}

// ---------------- MFMA GEMM + fused attention dots ----------------
// out_bf16[rows,N] = A[rows,K] @ Wt^T; es/ed[row][h] = dot(xW_row_head, a_src/a_dst[h])
// from fp32 accumulators. C/D layout (m89-verified): row=quad*4+rg, col=ct*16+l16.
template <int K, int N, int HEADS, bool AF32>
__global__ __launch_bounds__(256) void k_mgemm(const void* __restrict__ Ap,
                                               const unsigned short* __restrict__ Bt,
                                               const float* __restrict__ asrc,
                                               const float* __restrict__ adst,
                                               unsigned short* __restrict__ out,
                                               float* __restrict__ es,
                                               float* __restrict__ ed, int rows) {
    constexpr int LDP = K + 8;  // bf16 elems; rows stay 16B-aligned, conflicts <=2-way (free)
    __shared__ unsigned short As[64 * LDP];
    const int tid = threadIdx.x;
    const int r0 = blockIdx.x * 64;
    if (AF32) {
        const float* A = (const float*)Ap;
        for (int i = tid; i < 16 * K; i += 256) {
            int r = i / (K / 4), c4 = i % (K / 4);
            int row = r0 + r;
            float4 v = (row < rows) ? *(const float4*)&A[(size_t)row * K + c4 * 4]
                                    : make_float4(0.f, 0.f, 0.f, 0.f);
            ushort4 u;
            u.x = f2b(v.x); u.y = f2b(v.y); u.z = f2b(v.z); u.w = f2b(v.w);
            *(ushort4*)&As[r * LDP + c4 * 4] = u;
        }
    } else {
        const unsigned short* A = (const unsigned short*)Ap;
        for (int i = tid; i < 8 * K; i += 256) {
            int r = i / (K / 8), c8 = i % (K / 8);
            int row = r0 + r;
            uint4 v;
            if (row < rows) v = *(const uint4*)&A[(size_t)row * K + c8 * 8];
            else { v.x = v.y = v.z = v.w = 0; }
            *(uint4*)&As[r * LDP + c8 * 8] = v;
        }
    }
    __syncthreads();
    const int w = tid >> 6, lane = tid & 63;
    const int quad = lane >> 4, l16 = lane & 15;
    const int gr0 = r0 + w * 16 + quad * 4;
    bf16x8 afrag[K / 32];
#pragma unroll
    for (int kk = 0; kk < K / 32; ++kk)
        afrag[kk] = *(const bf16x8*)&As[(w * 16 + l16) * LDP + kk * 32 + quad * 8];
    float sacc[4] = {0.f, 0.f, 0.f, 0.f};
    float dacc[4] = {0.f, 0.f, 0.f, 0.f};
#pragma unroll 1
    for (int ct = 0; ct < N / 16; ++ct) {
        floatx4 acc = {0.f, 0.f, 0.f, 0.f};
#pragma unroll
        for (int kk = 0; kk < K / 32; ++kk) {
            const bf16x8 bfrag =
                *(const bf16x8*)&Bt[(size_t)(ct * 16 + l16) * K + kk * 32 + quad * 8];
            acc = __builtin_amdgcn_mfma_f32_16x16x32_bf16(afrag[kk], bfrag, acc, 0, 0, 0);
        }
        const int gc = ct * 16 + l16;
        const int hh = gc >> 6;  // head = gc/64 (0 when HEADS==1)
        const int f = gc & 63;
        const float as = asrc[hh * 64 + f];
        const float ad = adst[hh * 64 + f];
#pragma unroll
        for (int rg = 0; rg < 4; ++rg) {
            sacc[rg] = fmaf(acc[rg], as, sacc[rg]);
            dacc[rg] = fmaf(acc[rg], ad, dacc[rg]);
        }
#pragma unroll
        for (int rg = 0; rg < 4; ++rg) {
            int gr = gr0 + rg;
            if (gr < rows) out[(size_t)gr * N + gc] = f2b(acc[rg]);
        }
        if ((ct & 3) == 3) {
#pragma unroll
            for (int rg = 0; rg < 4; ++rg) {
                float s = sacc[rg], d = dacc[rg];
                for (int o = 1; o < 16; o <<= 1) {
                    s += __shfl_xor(s, o);
                    d += __shfl_xor(d, o);
                }
                if (l16 == 0) {
                    int gr = gr0 + rg;
                    if (gr < rows) {
                        es[(size_t)gr * HEADS + hh] = s;
                        ed[(size_t)gr * HEADS + hh] = d;
                    }
                }
                sacc[rg] = 0.f;
                dacc[rg] = 0.f;
            }
        }
    }
}

// ---------------- GAT layer 1: H=4, F=64, out 256 (bf16), + bias + relu ----------------
// ONE 16-lane group per dst node (4 nodes/wave, degree-sorted descending via perm).
// Lane t owns cols t*16..t*16+15 exclusively -> no reductions. 16-edge chunks staged
// to LDS (wave-synchronous); inner loop 4 edges/iter = 8 outstanding uint4 gathers.
// LDS p zero-padded past dg. No max-subtraction (scores O(1), softmax shift-invariant).
__global__ __launch_bounds__(256) void k_gat1(
    const unsigned short* __restrict__ xW, const float* __restrict__ es, const float* __restrict__ ed,
    const int* __restrict__ offs, const int* __restrict__ deg, const int* __restrict__ csr,
    const int* __restrict__ perm, const float* __restrict__ bias, unsigned short* __restrict__ out) {
    __shared__ float ps[4][4 * 68];  // [wave][grp*68 + j*4 + h]
    __shared__ int sbuf[4][64];      // [wave][grp*16 + j]
    const int wv = threadIdx.x >> 6;
    const int lane = threadIdx.x & 63;
    const int grp = lane >> 4, t = lane & 15;
    const int h = t >> 2;
    const int pidx = blockIdx.x * 16 + wv * 4 + grp;  // grid exact: 3125*16 = 50000
    const int n = perm[pidx];
    const int off = offs[n];
    const int dg = deg[n];
    const float4 edv = *(const float4*)&ed[n * 4];
    const int cb = t * 16;

    float acc[16];
#pragma unroll
    for (int k = 0; k < 16; ++k) acc[k] = 0.f;
    float dsum = 0.f;

    for (int base = 0; base < dg; base += 16) {
        const int idx = base + t;
        int s_l = 0;
        float p0 = 0.f, p1 = 0.f, p2 = 0.f, p3 = 0.f;
        if (idx < dg) {
            s_l = csr[off + idx];
            const float4 ev = *(const float4*)&es[s_l * 4];
            p0 = __expf(lrelu(ev.x + edv.x));
            p1 = __expf(lrelu(ev.y + edv.y));
            p2 = __expf(lrelu(ev.z + edv.z));
            p3 = __expf(lrelu(ev.w + edv.w));
        }
        *(float4*)&ps[wv][grp * 68 + t * 4] = make_float4(p0, p1, p2, p3);
        sbuf[wv][grp * 16 + t] = s_l;
        const int cnt = min(16, dg - base);
        const int cntR = (cnt + 3) & ~3;
        for (int j = 0; j < cntR; j += 4) {
            const float pa = ps[wv][grp * 68 + (j + 0) * 4 + h];
            const float pb = ps[wv][grp * 68 + (j + 1) * 4 + h];
            const float pc = ps[wv][grp * 68 + (j + 2) * 4 + h];
            const float pd = ps[wv][grp * 68 + (j + 3) * 4 + h];
            const int sa = sbuf[wv][grp * 16 + j + 0];
            const int sb = sbuf[wv][grp * 16 + j + 1];
            const int sc = sbuf[wv][grp * 16 + j + 2];
            const int sd = sbuf[wv][grp * 16 + j + 3];
            const uint4 a0 = *(const uint4*)&xW[(size_t)sa * 256 + cb];
            const uint4 a1 = *(const uint4*)&xW[(size_t)sa * 256 + cb + 8];
            const uint4 b0 = *(const uint4*)&xW[(size_t)sb * 256 + cb];
            const uint4 b1 = *(const uint4*)&xW[(size_t)sb * 256 + cb + 8];
            const uint4 c0 = *(const uint4*)&xW[(size_t)sc * 256 + cb];
            const uint4 c1 = *(const uint4*)&xW[(size_t)sc * 256 + cb + 8];
            const uint4 d0 = *(const uint4*)&xW[(size_t)sd * 256 + cb];
            const uint4 d1 = *(const uint4*)&xW[(size_t)sd * 256 + cb + 8];
            dsum += (pa + pb) + (pc + pd);
            acc[0]  = fmaf(pa, blo(a0.x), acc[0]);
            acc[1]  = fmaf(pa, bhi(a0.x), acc[1]);
            acc[2]  = fmaf(pa, blo(a0.y), acc[2]);
            acc[3]  = fmaf(pa, bhi(a0.y), acc[3]);
            acc[4]  = fmaf(pa, blo(a0.z), acc[4]);
            acc[5]  = fmaf(pa, bhi(a0.z), acc[5]);
            acc[6]  = fmaf(pa, blo(a0.w), acc[6]);
            acc[7]  = fmaf(pa, bhi(a0.w), acc[7]);
            acc[8]  = fmaf(pa, blo(a1.x), acc[8]);
            acc[9]  = fmaf(pa, bhi(a1.x), acc[9]);
            acc[10] = fmaf(pa, blo(a1.y), acc[10]);
            acc[11] = fmaf(pa, bhi(a1.y), acc[11]);
            acc[12] = fmaf(pa, blo(a1.z), acc[12]);
            acc[13] = fmaf(pa, bhi(a1.z), acc[13]);
            acc[14] = fmaf(pa, blo(a1.w), acc[14]);
            acc[15] = fmaf(pa, bhi(a1.w), acc[15]);
            acc[0]  = fmaf(pb, blo(b0.x), acc[0]);
            acc[1]  = fmaf(pb, bhi(b0.x), acc[1]);
            acc[2]  = fmaf(pb, blo(b0.y), acc[2]);
            acc[3]  = fmaf(pb, bhi(b0.y), acc[3]);
            acc[4]  = fmaf(pb, blo(b0.z), acc[4]);
            acc[5]  = fmaf(pb, bhi(b0.z), acc[5]);
            acc[6]  = fmaf(pb, blo(b0.w), acc[6]);
            acc[7]  = fmaf(pb, bhi(b0.w), acc[7]);
            acc[8]  = fmaf(pb, blo(b1.x), acc[8]);
            acc[9]  = fmaf(pb, bhi(b1.x), acc[9]);
            acc[10] = fmaf(pb, blo(b1.y), acc[10]);
            acc[11] = fmaf(pb, bhi(b1.y), acc[11]);
            acc[12] = fmaf(pb, blo(b1.z), acc[12]);
            acc[13] = fmaf(pb, bhi(b1.z), acc[13]);
            acc[14] = fmaf(pb, blo(b1.w), acc[14]);
            acc[15] = fmaf(pb, bhi(b1.w), acc[15]);
            acc[0]  = fmaf(pc, blo(c0.x), acc[0]);
            acc[1]  = fmaf(pc, bhi(c0.x), acc[1]);
            acc[2]  = fmaf(pc, blo(c0.y), acc[2]);
            acc[3]  = fmaf(pc, bhi(c0.y), acc[3]);
            acc[4]  = fmaf(pc, blo(c0.z), acc[4]);
            acc[5]  = fmaf(pc, bhi(c0.z), acc[5]);
            acc[6]  = fmaf(pc, blo(c0.w), acc[6]);
            acc[7]  = fmaf(pc, bhi(c0.w), acc[7]);
            acc[8]  = fmaf(pc, blo(c1.x), acc[8]);
            acc[9]  = fmaf(pc, bhi(c1.x), acc[9]);
            acc[10] = fmaf(pc, blo(c1.y), acc[10]);
            acc[11] = fmaf(pc, bhi(c1.y), acc[11]);
            acc[12] = fmaf(pc, blo(c1.z), acc[12]);
            acc[13] = fmaf(pc, bhi(c1.z), acc[13]);
            acc[14] = fmaf(pc, blo(c1.w), acc[14]);
            acc[15] = fmaf(pc, bhi(c1.w), acc[15]);
            acc[0]  = fmaf(pd, blo(d0.x), acc[0]);
            acc[1]  = fmaf(pd, bhi(d0.x), acc[1]);
            acc[2]  = fmaf(pd, blo(d0.y), acc[2]);
            acc[3]  = fmaf(pd, bhi(d0.y), acc[3]);
            acc[4]  = fmaf(pd, blo(d0.z), acc[4]);
            acc[5]  = fmaf(pd, bhi(d0.z), acc[5]);
            acc[6]  = fmaf(pd, blo(d0.w), acc[6]);
            acc[7]  = fmaf(pd, bhi(d0.w), acc[7]);
            acc[8]  = fmaf(pd, blo(d1.x), acc[8]);
            acc[9]  = fmaf(pd, bhi(d1.x), acc[9]);
            acc[10] = fmaf(pd, blo(d1.y), acc[10]);
            acc[11] = fmaf(pd, bhi(d1.y), acc[11]);
            acc[12] = fmaf(pd, blo(d1.z), acc[12]);
            acc[13] = fmaf(pd, bhi(d1.z), acc[13]);
            acc[14] = fmaf(pd, blo(d1.w), acc[14]);
            acc[15] = fmaf(pd, bhi(d1.w), acc[15]);
        }
    }
    const float inv = 1.0f / fmaxf(dsum, 1e-16f);
#pragma unroll
    for (int k4 = 0; k4 < 16; k4 += 4) {
        const int c = cb + k4;
        const float4 bv = *(const float4*)&bias[c];
        ushort4 o4;
        o4.x = f2b(fmaxf(fmaf(acc[k4 + 0], inv, bv.x), 0.f));
        o4.y = f2b(fmaxf(fmaf(acc[k4 + 1], inv, bv.y), 0.f));
        o4.z = f2b(fmaxf(fmaf(acc[k4 + 2], inv, bv.z), 0.f));
        o4.w = f2b(fmaxf(fmaf(acc[k4 + 3], inv, bv.w), 0.f));
        *(ushort4*)&out[(size_t)n * 256 + c] = o4;
    }
}

// ---------------- GAT layers 2-4: H=1, F=64, + bias + BN + relu (+ residual) ----------------
// ONE 8-lane group per node (8 nodes/wave, degree-sorted descending). Lane t owns
// cols t*8..t*8+7; no reductions; 8-edge chunks staged to LDS; 4 edges/iter in flight.
template <bool RES>
__global__ __launch_bounds__(256) void k_gatL(
    const unsigned short* __restrict__ xW, const float* __restrict__ es, const float* __restrict__ ed,
    const int* __restrict__ offs, const int* __restrict__ deg, const int* __restrict__ csr,
    const int* __restrict__ perm, const float* __restrict__ bias, const float* __restrict__ gam,
    const float* __restrict__ bet, float* __restrict__ h, unsigned short* __restrict__ hb) {
    __shared__ float ps[4][64];  // [wave][grp*8 + j]
    __shared__ int sbuf[4][64];
    const int wv = threadIdx.x >> 6;
    const int lane = threadIdx.x & 63;
    const int grp = lane >> 3, t = lane & 7;
    const int pidx = blockIdx.x * 32 + wv * 8 + grp;
    if (pidx >= N_NODES) return;
    const int n = perm[pidx];
    const int off = offs[n];
    const int dg = deg[n];
    const float edn = ed[n];
    const int cb = t * 8;

    float acc[8];
#pragma unroll
    for (int k = 0; k < 8; ++k) acc[k] = 0.f;
    float dsum = 0.f;

    for (int base = 0; base < dg; base += 8) {
        const int idx = base + t;
        int s_l = 0;
        float p_l = 0.f;
        if (idx < dg) {
            s_l = csr[off + idx];
            p_l = __expf(lrelu(es[s_l] + edn));
        }
        ps[wv][grp * 8 + t] = p_l;
        sbuf[wv][grp * 8 + t] = s_l;
        const int cnt = min(8, dg - base);
        const int cntR = (cnt + 3) & ~3;
        for (int j = 0; j < cntR; j += 4) {
            const float pa = ps[wv][grp * 8 + j + 0];
            const float pb = ps[wv][grp * 8 + j + 1];
            const float pc = ps[wv][grp * 8 + j + 2];
            const float pd = ps[wv][grp * 8 + j + 3];
            const int sa = sbuf[wv][grp * 8 + j + 0];
            const int sb = sbuf[wv][grp * 8 + j + 1];
            const int sc = sbuf[wv][grp * 8 + j + 2];
            const int sd = sbuf[wv][grp * 8 + j + 3];
            const uint4 a = *(const uint4*)&xW[(size_t)sa * 64 + cb];
            const uint4 b = *(const uint4*)&xW[(size_t)sb * 64 + cb];
            const uint4 c = *(const uint4*)&xW[(size_t)sc * 64 + cb];
            const uint4 d = *(const uint4*)&xW[(size_t)sd * 64 + cb];
            dsum += (pa + pb) + (pc + pd);
            acc[0] = fmaf(pa, blo(a.x), acc[0]);
            acc[1] = fmaf(pa, bhi(a.x), acc[1]);
            acc[2] = fmaf(pa, blo(a.y), acc[2]);
            acc[3] = fmaf(pa, bhi(a.y), acc[3]);
            acc[4] = fmaf(pa, blo(a.z), acc[4]);
            acc[5] = fmaf(pa, bhi(a.z), acc[5]);
            acc[6] = fmaf(pa, blo(a.w), acc[6]);
            acc[7] = fmaf(pa, bhi(a.w), acc[7]);
            acc[0] = fmaf(pb, blo(b.x), acc[0]);
            acc[1] = fmaf(pb, bhi(b.x), acc[1]);
            acc[2] = fmaf(pb, blo(b.y), acc[2]);
            acc[3] = fmaf(pb, bhi(b.y), acc[3]);
            acc[4] = fmaf(pb, blo(b.z), acc[4]);
            acc[5] = fmaf(pb, bhi(b.z), acc[5]);
            acc[6] = fmaf(pb, blo(b.w), acc[6]);
            acc[7] = fmaf(pb, bhi(b.w), acc[7]);
            acc[0] = fmaf(pc, blo(c.x), acc[0]);
            acc[1] = fmaf(pc, bhi(c.x), acc[1]);
            acc[2] = fmaf(pc, blo(c.y), acc[2]);
            acc[3] = fmaf(pc, bhi(c.y), acc[3]);
            acc[4] = fmaf(pc, blo(c.z), acc[4]);
            acc[5] = fmaf(pc, bhi(c.z), acc[5]);
            acc[6] = fmaf(pc, blo(c.w), acc[6]);
            acc[7] = fmaf(pc, bhi(c.w), acc[7]);
            acc[0] = fmaf(pd, blo(d.x), acc[0]);
            acc[1] = fmaf(pd, bhi(d.x), acc[1]);
            acc[2] = fmaf(pd, blo(d.y), acc[2]);
            acc[3] = fmaf(pd, bhi(d.y), acc[3]);
            acc[4] = fmaf(pd, blo(d.z), acc[4]);
            acc[5] = fmaf(pd, bhi(d.z), acc[5]);
            acc[6] = fmaf(pd, blo(d.w), acc[6]);
            acc[7] = fmaf(pd, bhi(d.w), acc[7]);
        }
    }
    const float inv = 1.0f / fmaxf(dsum, 1e-16f);
    float hn[8];
#pragma unroll
    for (int k = 0; k < 8; ++k) {
        const int c = cb + k;
        const float y = fmaf(acc[k], inv, bias[c]);
        const float z = fmaxf(fmaf(gam[c] * y, BN_RSQ, bet[c]), 0.f);
        hn[k] = RES ? h[(size_t)n * 64 + c] + z : z;
    }
    *(float4*)&h[(size_t)n * 64 + cb] = make_float4(hn[0], hn[1], hn[2], hn[3]);
    *(float4*)&h[(size_t)n * 64 + cb + 4] = make_float4(hn[4], hn[5], hn[6], hn[7]);
    ushort4 u0, u1;
    u0.x = f2b(hn[0]); u0.y = f2b(hn[1]); u0.z = f2b(hn[2]); u0.w = f2b(hn[3]);
    u1.x = f2b(hn[4]); u1.y = f2b(hn[5]); u1.z = f2b(hn[6]); u1.w = f2b(hn[7]);
    *(ushort4*)&hb[(size_t)n * 64 + cb] = u0;
    *(ushort4*)&hb[(size_t)n * 64 + cb + 4] = u1;
}

// ---------------- mean pool: one block per graph, contiguous node range, no atomics ----------------
__global__ __launch_bounds__(256) void k_pool2(const float* __restrict__ h,
                                               const int* __restrict__ bounds,
                                               float* __restrict__ hp) {
    __shared__ float part[4][64];
    const int g = blockIdx.x;
    const int lane = threadIdx.x & 63;
    const int wid = threadIdx.x >> 6;
    const int s = bounds[g], e = bounds[g + 1];
    float acc = 0.f;
    for (int n = s + wid; n < e; n += 4) acc += h[n * 64 + lane];
    part[wid][lane] = acc;
    __syncthreads();
    if (wid == 0) {
        float v = part[0][lane] + part[1][lane] + part[2][lane] + part[3][lane];
        hp[g * 64 + lane] = v / fmaxf((float)(e - s), 1.0f);
    }
}

// ---------------- MLP head, single block (hp already mean-pooled) ----------------
__global__ __launch_bounds__(256) void k_head(const float* __restrict__ hpg,
                                              const float* __restrict__ Wh1,
                                              const float* __restrict__ bh1,
                                              const float* __restrict__ Wh2,
                                              const float* __restrict__ bh2,
                                              float* __restrict__ out) {
    __shared__ float hp[64 * 64];
    __shared__ float t1[64 * 128];
    const int tid = threadIdx.x;
    for (int i = tid; i < 64 * 64; i += 256) hp[i] = hpg[i];
    __syncthreads();
    for (int i = tid; i < 64 * 128; i += 256) {
        int g = i >> 7, j = i & 127;
        float s = bh1[j];
        for (int k = 0; k < 64; ++k) s = fmaf(hp[g * 64 + k], Wh1[k * 128 + j], s);
        t1[i] = fmaxf(s, 0.f);
    }
    __syncthreads();
    for (int i = tid; i < 640; i += 256) {
        int g = i / 10, j = i - g * 10;
        float s = bh2[j];
        for (int k = 0; k < 128; ++k) s = fmaf(t1[g * 128 + k], Wh2[k * 10 + j], s);
        out[i] = s;
    }
}

extern "C" void kernel_launch(void* const* d_in, const int* in_sizes, int n_in,
                              void* d_out, int out_size, void* d_ws, size_t ws_size,
                              hipStream_t stream) {
    const float* x = (const float*)d_in[1];
    const int* ei = (const int*)d_in[2];
    const int* batch = (const int*)d_in[3];
    const float* W1 = (const float*)d_in[4];
    const float* a_src1 = (const float*)d_in[5];
    const float* a_dst1 = (const float*)d_in[6];
    const float* b1 = (const float*)d_in[7];
    const float* W2 = (const float*)d_in[8];
    const float* a_src2 = (const float*)d_in[9];
    const float* a_dst2 = (const float*)d_in[10];
    const float* b2 = (const float*)d_in[11];
    const float* g2 = (const float*)d_in[12];
    const float* be2 = (const float*)d_in[13];
    const float* W3 = (const float*)d_in[14];
    const float* a_src3 = (const float*)d_in[15];
    const float* a_dst3 = (const float*)d_in[16];
    const float* b3 = (const float*)d_in[17];
    const float* g3 = (const float*)d_in[18];
    const float* be3 = (const float*)d_in[19];
    const float* W4 = (const float*)d_in[20];
    const float* a_src4 = (const float*)d_in[21];
    const float* a_dst4 = (const float*)d_in[22];
    const float* b4 = (const float*)d_in[23];
    const float* g4 = (const float*)d_in[24];
    const float* be4 = (const float*)d_in[25];
    const float* Wh1 = (const float*)d_in[26];
    const float* bh1 = (const float*)d_in[27];
    const float* Wh2 = (const float*)d_in[28];
    const float* bh2 = (const float*)d_in[29];
    float* out = (float*)d_out;

    // workspace layout
    char* p = (char*)d_ws;
    auto alloc = [&](size_t bytes) {
        void* r = (void*)p;
        p += (bytes + 255) & ~(size_t)255;
        return r;
    };
    unsigned short* bufA = (unsigned short*)alloc((size_t)N_NODES * 256 * 2);  // xW bf16 per layer
    unsigned short* x1b = (unsigned short*)alloc((size_t)N_NODES * 256 * 2);   // x1 bf16
    float* h = (float*)alloc((size_t)N_NODES * 64 * 4);                        // h fp32
    unsigned short* hb = (unsigned short*)alloc((size_t)N_NODES * 64 * 2);     // h bf16
    float* es1 = (float*)alloc((size_t)N_NODES * 4 * 4);
    float* ed1 = (float*)alloc((size_t)N_NODES * 4 * 4);
    float* esL = (float*)alloc((size_t)N_NODES * 4);
    float* edL = (float*)alloc((size_t)N_NODES * 4);
    int* offs = (int*)alloc((size_t)N_NODES * 4);
    int* csr = (int*)alloc((size_t)N_EDGES * 4);
    int* perm = (int*)alloc((size_t)N_NODES * 4);
    int* bounds = (int*)alloc((size_t)(N_GRAPHS + 1) * 4);
    int* bh_hist = (int*)alloc((size_t)NB_SCAN * 64 * 4);
    int* bb = (int*)alloc((size_t)NB_SCAN * 64 * 4);
    float* hpool = (float*)alloc((size_t)N_GRAPHS * 64 * 4);
    unsigned short* Wt1 = (unsigned short*)alloc((size_t)128 * 256 * 2);
    unsigned short* Wt2 = (unsigned short*)alloc((size_t)256 * 64 * 2);
    unsigned short* Wt3 = (unsigned short*)alloc((size_t)64 * 64 * 2);
    unsigned short* Wt4 = (unsigned short*)alloc((size_t)64 * 64 * 2);
    char* z0 = p;  // everything below gets zeroed each call
    int* deg = (int*)alloc((size_t)N_NODES * 4);
    int* cur = (int*)alloc((size_t)N_NODES * 4);
    int* total = (int*)alloc(256);
    size_t zbytes = (size_t)(p - z0);
    hipMemsetAsync(z0, 0, zbytes, stream);

    const int edgeBlocks = (N_EDGES + 255) / 256;
    const int mgemmBlocks = (N_NODES + 63) / 64;
    const int gat1Blocks = (N_NODES + 15) / 16;  // 3125 exact
    const int gatLBlocks = (N_NODES + 31) / 32;

    // fused prep: degree count + weight bf16 transposes
    k_prep<<<edgeBlocks, 256, 0, stream>>>(ei, deg, W1, W2, W3, W4, Wt1, Wt2, Wt3, Wt4);

    // CSR offsets + LPT histogram + graph bounds; bucket scan; merged fill+perm
    k_offs<<<NB_SCAN, 256, 0, stream>>>(deg, offs, total, batch, bounds, bh_hist);
    k_pscan<<<1, 256, 0, stream>>>(bh_hist, bb);
    k_fillperm<<<edgeBlocks, 256, 0, stream>>>(ei, offs, cur, csr, deg, bb, perm);

    // layer 1: GAT(128 -> 4x64, concat) + relu  (dots fused into GEMM epilogue)
    k_mgemm<128, 256, 4, true><<<mgemmBlocks, 256, 0, stream>>>(x, Wt1, a_src1, a_dst1,
                                                                bufA, es1, ed1, N_NODES);
    k_gat1<<<gat1Blocks, 256, 0, stream>>>(bufA, es1, ed1, offs, deg, csr, perm, b1, x1b);

    // layer 2: GAT(256 -> 64) + BN + relu
    k_mgemm<256, 64, 1, false><<<mgemmBlocks, 256, 0, stream>>>(x1b, Wt2, a_src2, a_dst2,
                                                                bufA, esL, edL, N_NODES);
    k_gatL<false><<<gatLBlocks, 256, 0, stream>>>(bufA, esL, edL, offs, deg, csr, perm, b2, g2, be2, h, hb);

    // layer 3: residual GAT(64 -> 64) + BN + relu
    k_mgemm<64, 64, 1, false><<<mgemmBlocks, 256, 0, stream>>>(hb, Wt3, a_src3, a_dst3,
                                                               bufA, esL, edL, N_NODES);
    k_gatL<true><<<gatLBlocks, 256, 0, stream>>>(bufA, esL, edL, offs, deg, csr, perm, b3, g3, be3, h, hb);

    // layer 4: residual GAT(64 -> 64) + BN + relu
    k_mgemm<64, 64, 1, false><<<mgemmBlocks, 256, 0, stream>>>(hb, Wt4, a_src4, a_dst4,
                                                               bufA, esL, edL, N_NODES);
    k_gatL<true><<<gatLBlocks, 256, 0, stream>>>(bufA, esL, edL, offs, deg, csr, perm, b4, g4, be4, h, hb);

    // pool + head (batch sorted -> contiguous ranges, no atomics)
    k_pool2<<<N_GRAPHS, 256, 0, stream>>>(h, bounds, hpool);
    k_head<<<1, 256, 0, stream>>>(hpool, Wh1, bh1, Wh2, bh2, out);
}